// Round 3
// baseline (148.048 us; speedup 1.0000x reference)
//
#include <hip/hip_runtime.h>
#include <hip/hip_bf16.h>
#include <math.h>

// Problem constants (fixed by reference: b=2, h=w=64, dim=256, attn_dim=128, HEAD=4)
#define N_TOK 4096
#define C_DIM 256
#define A_DIM 128
#define HEADS 4
#define HD    32
#define NBAT  2
#define BH    (NBAT * HEADS)

// (1/sqrt(32)) * log2(e) — folded into Wq at pack time
#define SCALE_LOG2E 0.25503521f

#define SPLITS 8
#define KEYS_PER_SPLIT (N_TOK / SPLITS)

typedef __attribute__((ext_vector_type(8))) short short8;   // 8 bf16 frag
typedef __attribute__((ext_vector_type(4))) short short4_t; // 4 bf16
typedef __attribute__((ext_vector_type(4))) float floatx4;  // MFMA C/D frag

__device__ __forceinline__ unsigned short f2bf(float f) {   // RNE
    unsigned int u = __float_as_uint(f);
    u = (u + 0x7fffu + ((u >> 16) & 1u)) >> 16;
    return (unsigned short)u;
}
__device__ __forceinline__ float bf2f(unsigned short u) {
    return __uint_as_float((unsigned int)u << 16);
}
// pack two positive floats to bf16x2 (round-half-up), lo = a, hi = b
__device__ __forceinline__ unsigned int pack2(float a, float b) {
    unsigned int lo = (__float_as_uint(a) + 0x8000u) >> 16;
    unsigned int hi = (__float_as_uint(b) + 0x8000u) & 0xffff0000u;
    return hi | lo;
}

// ---------------------------------------------------------------------------
// In-register quad transpose of packed bf16 key-pairs.
// Input per lane (quad q): a0 = keys(4q,4q+1), a1 = keys(4q+2,4q+3)  [frag0]
//                          a2 = keys(16+4q,16+4q+1), a3 = keys(16+4q+2,16+4q+3) [frag1]
// (i.e. source word (qs,j) holds pair-index m = 8*(j>>1) + 2*qs + (j&1))
// Output: PV A-frag — lane (q) holds keys 8q..8q+7 = pair-indices 4q..4q+3.
// 2-level butterfly:
//   L1: permlane32_swap (half<->half): res0 = [x.lo|y.lo], res1 = [x.hi|y.hi]
//   L2: permlane16_swap (quad<->quad within half): vdst=[x.q0,y.q0,x.q2,y.q2]
// yields t0..t3 = m = 4q+0..3 exactly. Replaces the former P_lds round-trip
// (8 ds_write_b32 + ds_read_b128 + 2 lgkmcnt chains) with 4 VALU-ish ops.
// ---------------------------------------------------------------------------
__device__ __forceinline__ short8 quad_xpose(unsigned int a0, unsigned int a1,
                                             unsigned int a2, unsigned int a3,
                                             int lane)
{
    union { unsigned int u[4]; short8 s; } cv;
#if __has_builtin(__builtin_amdgcn_permlane32_swap) && __has_builtin(__builtin_amdgcn_permlane16_swap)
    (void)lane;
    auto s0 = __builtin_amdgcn_permlane32_swap(a0, a2, false, false);
    auto s1 = __builtin_amdgcn_permlane32_swap(a1, a3, false, false);
    auto t0 = __builtin_amdgcn_permlane16_swap(s0[0], s0[1], false, false);
    auto t1 = __builtin_amdgcn_permlane16_swap(s1[0], s1[1], false, false);
    cv.u[0] = t0[0]; cv.u[1] = t1[0]; cv.u[2] = t0[1]; cv.u[3] = t1[1];
#else
    // Fallback: shfl_xor(32) for the half swap, ds_swizzle xor-16 for quads.
    const int hi32 = (lane >> 5) & 1;
    const int u16  = (lane >> 4) & 1;
    unsigned int x0 = __shfl_xor(a2, 32), x2 = __shfl_xor(a0, 32);
    unsigned int r0 = hi32 ? x0 : a0;     // [a0.lo | a2.lo]
    unsigned int r1 = hi32 ? a2 : x2;     // [a0.hi | a2.hi]
    unsigned int y0 = __shfl_xor(a3, 32), y2 = __shfl_xor(a1, 32);
    unsigned int r0b = hi32 ? y0 : a1;
    unsigned int r1b = hi32 ? a3 : y2;
    unsigned int w0 = (unsigned int)__builtin_amdgcn_ds_swizzle((int)r1, 0x401F);
    unsigned int w1 = (unsigned int)__builtin_amdgcn_ds_swizzle((int)r0, 0x401F);
    unsigned int w2 = (unsigned int)__builtin_amdgcn_ds_swizzle((int)r1b, 0x401F);
    unsigned int w3 = (unsigned int)__builtin_amdgcn_ds_swizzle((int)r0b, 0x401F);
    cv.u[0] = u16 ? w0 : r0;
    cv.u[1] = u16 ? w2 : r0b;
    cv.u[2] = u16 ? r1 : w1;
    cv.u[3] = u16 ? r1b : w3;
#endif
    return cv.s;
}

// ---------------------------------------------------------------------------
// K0: pack weights fp32 -> bf16 in B-fragment order.
// Layout: Wp[wid][step s][tile t][lane][j]  (wid: 0=Wq(scaled) 1=Wk 2=Wv 3=Wo)
// ---------------------------------------------------------------------------
__global__ __launch_bounds__(256) void wpack_kernel(
    const float* __restrict__ Wq, const float* __restrict__ Wk,
    const float* __restrict__ Wv, const float* __restrict__ Wo,
    unsigned short* __restrict__ Wp)
{
    const int chunk = blockIdx.x * 256 + threadIdx.x;  // [0, 16384): 8 shorts each
    const int wid = chunk >> 12;
    const int c = chunk & 4095;
    const int lane = c & 63, quad = lane >> 4, l15 = lane & 15;
    short8 v;
    if (wid < 3) {
        const int s = c >> 9, t = (c >> 6) & 7;
        const float* W = (wid == 0) ? Wq : ((wid == 1) ? Wk : Wv);
        const float scale = (wid == 0) ? SCALE_LOG2E : 1.0f;
        const int src = (s * 32 + quad * 8) * A_DIM + t * 16 + l15;
        #pragma unroll
        for (int j = 0; j < 8; j++) v[j] = (short)f2bf(W[src + j * A_DIM] * scale);
    } else {
        const int s = c >> 10, t = (c >> 6) & 15;
        const int src = (s * 32 + quad * 8) * C_DIM + t * 16 + l15;
        #pragma unroll
        for (int j = 0; j < 8; j++) v[j] = (short)f2bf(Wo[src + j * C_DIM]);
    }
    *(short8*)(Wp + (long)chunk * 8) = v;
}

// ---------------------------------------------------------------------------
// K1: QKV projection via MFMA. 512 blocks x 4 waves (unchanged).
// ---------------------------------------------------------------------------
__global__ __launch_bounds__(256) void qkv_kernel(
    const float* __restrict__ query, const float* __restrict__ context,
    const unsigned short* __restrict__ Wp,
    unsigned short* __restrict__ Qb, unsigned short* __restrict__ Kb,
    unsigned short* __restrict__ Vb)
{
    __shared__ __align__(16) unsigned short V_lds[128 * 18];  // [col][tok16+pad] 4.5KB

    const int tid = threadIdx.x;
    const int w = tid >> 6, lane = tid & 63;
    const int quad = lane >> 4, l15 = lane & 15;
    const int ch = w;                      // col quarter (32 cols)
    const long i0 = (long)blockIdx.x * 16;
    const long row = i0 + l15;

    const unsigned short* Wqp = Wp;
    const unsigned short* Wkp = Wp + 32768;
    const unsigned short* Wvp = Wp + 65536;

    floatx4 aQ[2] = {}, aK[2] = {}, aV[2] = {};

    for (int s = 0; s < 8; s++) {
        const float* qp = query + row * C_DIM + s * 32 + quad * 8;
        const float* cp = context + row * C_DIM + s * 32 + quad * 8;
        floatx4 q0 = *(const floatx4*)qp, q1 = *(const floatx4*)(qp + 4);
        floatx4 c0 = *(const floatx4*)cp, c1 = *(const floatx4*)(cp + 4);
        short8 aq, ac;
        #pragma unroll
        for (int j = 0; j < 4; j++) {
            aq[j] = (short)f2bf(q0[j]); aq[4 + j] = (short)f2bf(q1[j]);
            ac[j] = (short)f2bf(c0[j]); ac[4 + j] = (short)f2bf(c1[j]);
        }
        #pragma unroll
        for (int tp = 0; tp < 2; tp++) {
            const long fo = ((long)(s * 8 + ch * 2 + tp) * 64 + lane) * 8;
            short8 bq = *(const short8*)(Wqp + fo);
            short8 bk = *(const short8*)(Wkp + fo);
            short8 bv = *(const short8*)(Wvp + fo);
            aQ[tp] = __builtin_amdgcn_mfma_f32_16x16x32_bf16(aq, bq, aQ[tp], 0, 0, 0);
            aK[tp] = __builtin_amdgcn_mfma_f32_16x16x32_bf16(ac, bk, aK[tp], 0, 0, 0);
            aV[tp] = __builtin_amdgcn_mfma_f32_16x16x32_bf16(ac, bv, aV[tp], 0, 0, 0);
        }
    }

    const long b = i0 >> 12;
    const long n0 = i0 & (N_TOK - 1);
    const long nbase = n0 + quad * 4;
    #pragma unroll
    for (int tp = 0; tp < 2; tp++) {
        const int col = ch * 32 + tp * 16 + l15;
        const int h = col >> 5, d = col & 31;
        unsigned short* qdst = Qb + ((b * HEADS + h) * N_TOK + nbase) * HD + d;
        unsigned short* kdst = Kb + ((b * HEADS + h) * N_TOK + nbase) * HD + d;
        #pragma unroll
        for (int r = 0; r < 4; r++) {
            qdst[r * HD] = f2bf(aQ[tp][r]);
            kdst[r * HD] = f2bf(aK[tp][r]);
        }
        short4_t pv;
        #pragma unroll
        for (int r = 0; r < 4; r++) pv[r] = (short)f2bf(aV[tp][r]);
        *(short4_t*)&V_lds[col * 18 + quad * 4] = pv;
    }
    __syncthreads();

    {   // cooperative V^T write-out: 128 cols x 16 tokens; 16B chunks
        const int col = tid >> 1, seg = tid & 1;
        const int h = col >> 5, d = col & 31;
        unsigned short* dst = Vb + ((b * HEADS + h) * HD + d) * N_TOK + n0 + seg * 8;
        *(short8*)dst = *(const short8*)&V_lds[col * 18 + seg * 8];
    }
}

// ---------------------------------------------------------------------------
// K2: flash attention, no-max softmax, split-K=8, S^T formulation.
// ZERO-LDS / ZERO-BARRIER version:
//  - K and V fragments are read straight from global. With the XCD swizzle,
//    each (bh,z) group's K+V slice (64 KB) is read by 32 blocks pinned to one
//    XCD -> L1/L2 hits; latency hidden by independent waves instead of being
//    serialized through LDS staging + 2 __syncthreads per tile.
//  - P^T -> P transpose (quad-wise 4x4 of packed bf16 pairs) is done fully
//    in-register via v_permlane32_swap + v_permlane16_swap (quad_xpose),
//    removing the P_lds store->load round-trip from the softmax->PV chain.
//  - Denominator: per-lane column sums, quad-reduced once at the end.
// ---------------------------------------------------------------------------
__global__ __launch_bounds__(256, 4) void attn_kernel(
    const unsigned short* __restrict__ Qb, const unsigned short* __restrict__ Kb,
    const unsigned short* __restrict__ Vb,
    unsigned short* __restrict__ AO, float* __restrict__ Lbuf)
{
    const int tid  = threadIdx.x;
    const int w    = tid >> 6;
    const int lane = tid & 63;
    const int quad = lane >> 4;
    const int l15  = lane & 15;

    // XCD swizzle: blocks with equal (bh,z) share L%8 -> same XCD L2.
    const int L  = blockIdx.x;
    const int g  = (L & 7) + 8 * ((L >> 3) >> 5);  // group 0..63
    const int qb = (L >> 3) & 31;                  // q-block 0..31
    const int bh = g & 7;
    const int z  = g >> 3;
    const int i0 = qb * 128 + w * 32;

    const unsigned short* Qh = Qb + (long)bh * N_TOK * HD;
    const unsigned short* Kh = Kb + (long)bh * N_TOK * HD;
    const unsigned short* Vh = Vb + (long)bh * HD * N_TOK;

    const short8 qfA = *(const short8*)(Qh + (long)(i0 + l15) * HD + quad * 8);
    const short8 qfB = *(const short8*)(Qh + (long)(i0 + 16 + l15) * HD + quad * 8);

    floatx4 accA0 = {0.f,0.f,0.f,0.f}, accA1 = {0.f,0.f,0.f,0.f};
    floatx4 accB0 = {0.f,0.f,0.f,0.f}, accB1 = {0.f,0.f,0.f,0.f};
    float lAc = 0.f, lBc = 0.f;   // denom partial for query l15 (this lane's col)

    const int j_lo = z * KEYS_PER_SPLIT;

    // Per-lane fragment pointers; all other frags reachable via imm offsets
    // (K rows: 64 B; +16 rows = 1024 B, +32 = 2048 B, +48 = 3072 B; V: +32 tok
    // = 64 B) except V row +16 dims = 128 KB -> second pointer vp1.
    const unsigned short* kp  = Kh + (long)j_lo * HD + l15 * HD + quad * 8;
    const unsigned short* vp0 = Vh + (long)l15 * N_TOK + j_lo + quad * 8;
    const unsigned short* vp1 = vp0 + 16 * N_TOK;

    #pragma unroll 1
    for (int t = 0; t < KEYS_PER_SPLIT / 64; ++t) {
        // issue all 8 tile loads up front (L1/L2-resident)
        const short8 k00 = *(const short8*)(kp);            // keys  0..15 (rows l15)
        const short8 k10 = *(const short8*)(kp + 16 * HD);  // keys 16..31
        const short8 k01 = *(const short8*)(kp + 32 * HD);  // keys 32..47
        const short8 k11 = *(const short8*)(kp + 48 * HD);  // keys 48..63
        const short8 v00 = *(const short8*)(vp0);           // d=l15,    tok 0..31
        const short8 v10 = *(const short8*)(vp1);           // d=16+l15, tok 0..31
        const short8 v01 = *(const short8*)(vp0 + 32);      // d=l15,    tok 32..63
        const short8 v11 = *(const short8*)(vp1 + 32);      // d=16+l15, tok 32..63
        kp += 64 * HD; vp0 += 64; vp1 += 64;

        #pragma unroll
        for (int sub = 0; sub < 2; sub++) {
            const short8 kf0 = sub ? k01 : k00;
            const short8 kf1 = sub ? k11 : k10;
            const short8 vf0 = sub ? v01 : v00;
            const short8 vf1 = sub ? v11 : v10;

            const floatx4 zf = {0.f,0.f,0.f,0.f};
            // S^T = K · Q^T : C rows = keys, cols = queries
            floatx4 sA0 = __builtin_amdgcn_mfma_f32_16x16x32_bf16(kf0, qfA, zf, 0, 0, 0);
            floatx4 sA1 = __builtin_amdgcn_mfma_f32_16x16x32_bf16(kf1, qfA, zf, 0, 0, 0);
            floatx4 sB0 = __builtin_amdgcn_mfma_f32_16x16x32_bf16(kf0, qfB, zf, 0, 0, 0);
            floatx4 sB1 = __builtin_amdgcn_mfma_f32_16x16x32_bf16(kf1, qfB, zf, 0, 0, 0);

            floatx4 pA0, pA1, pB0, pB1;
            #pragma unroll
            for (int r = 0; r < 4; r++) {
                pA0[r] = __builtin_amdgcn_exp2f(sA0[r]);
                pA1[r] = __builtin_amdgcn_exp2f(sA1[r]);
                pB0[r] = __builtin_amdgcn_exp2f(sB0[r]);
                pB1[r] = __builtin_amdgcn_exp2f(sB1[r]);
                lAc += pA0[r] + pA1[r];
                lBc += pB0[r] + pB1[r];
            }

            // pack consecutive key pairs and transpose quads in-register
            short8 pfA = quad_xpose(pack2(pA0[0], pA0[1]), pack2(pA0[2], pA0[3]),
                                    pack2(pA1[0], pA1[1]), pack2(pA1[2], pA1[3]), lane);
            short8 pfB = quad_xpose(pack2(pB0[0], pB0[1]), pack2(pB0[2], pB0[3]),
                                    pack2(pB1[0], pB1[1]), pack2(pB1[2], pB1[3]), lane);

            accA0 = __builtin_amdgcn_mfma_f32_16x16x32_bf16(pfA, vf0, accA0, 0, 0, 0);
            accA1 = __builtin_amdgcn_mfma_f32_16x16x32_bf16(pfA, vf1, accA1, 0, 0, 0);
            accB0 = __builtin_amdgcn_mfma_f32_16x16x32_bf16(pfB, vf0, accB0, 0, 0, 0);
            accB1 = __builtin_amdgcn_mfma_f32_16x16x32_bf16(pfB, vf1, accB1, 0, 0, 0);
        }
    }

    // denom: sum the 4 quads holding the same query column
    lAc += __shfl_xor(lAc, 16); lAc += __shfl_xor(lAc, 32);
    lBc += __shfl_xor(lBc, 16); lBc += __shfl_xor(lBc, 32);

    const int b = bh >> 2, h = bh & 3;
    unsigned short* AOz = AO + (long)z * (NBAT * N_TOK * A_DIM);
    float* Lz = Lbuf + (long)z * (BH * N_TOK);
    if (quad == 0) {   // one lane per query writes the denominator
        Lz[(long)bh * N_TOK + i0 + l15]      = lAc;
        Lz[(long)bh * N_TOK + i0 + 16 + l15] = lBc;
    }
    #pragma unroll
    for (int r = 0; r < 4; r++) {
        // O C-frags: rows = queries quad*4+r; fetch that query's denom by shfl
        const float invA = 1.0f / __shfl(lAc, quad * 4 + r);
        const float invB = 1.0f / __shfl(lBc, quad * 4 + r);
        const long rowA = (long)b * N_TOK + i0 + quad * 4 + r;
        const long rowB = rowA + 16;
        AOz[rowA * A_DIM + h * HD + l15]      = f2bf(accA0[r] * invA);
        AOz[rowA * A_DIM + h * HD + 16 + l15] = f2bf(accA1[r] * invA);
        AOz[rowB * A_DIM + h * HD + l15]      = f2bf(accB0[r] * invB);
        AOz[rowB * A_DIM + h * HD + 16 + l15] = f2bf(accB1[r] * invB);
    }
}

// ---------------------------------------------------------------------------
// K3: split-K combine + out-projection via MFMA. 512 blocks x 4 waves
// (unchanged).
// ---------------------------------------------------------------------------
__global__ __launch_bounds__(256) void outproj_kernel(
    const unsigned short* __restrict__ AO, const float* __restrict__ Lbuf,
    const unsigned short* __restrict__ Wp, float* __restrict__ out)
{
    const int tid = threadIdx.x;
    const int w = tid >> 6, lane = tid & 63;
    const int quad = lane >> 4, l15 = lane & 15;
    const int ch = w;                       // col quarter (64 cols)
    const long i0 = (long)blockIdx.x * 16;
    const long row = i0 + l15;
    const int b = (int)(row >> 12);
    const int n = (int)(row & (N_TOK - 1));
    const unsigned short* Wop = Wp + 98304;

    floatx4 acc[4] = {};

    #pragma unroll
    for (int s = 0; s < 4; s++) {   // k-step == head s (32-aligned)
        float lz[SPLITS], lsum = 0.f;
        #pragma unroll
        for (int z = 0; z < SPLITS; z++) {
            lz[z] = Lbuf[(long)z * (BH * N_TOK) + (long)(b * HEADS + s) * N_TOK + n];
            lsum += lz[z];
        }
        const float inv = 1.0f / lsum;
        float vals[8] = {};
        #pragma unroll
        for (int z = 0; z < SPLITS; z++) {
            short8 az = *(const short8*)(AO + (long)z * (NBAT * N_TOK * A_DIM) +
                                         row * A_DIM + s * 32 + quad * 8);
            const float wz = lz[z] * inv;
            #pragma unroll
            for (int j = 0; j < 8; j++) vals[j] += wz * bf2f((unsigned short)az[j]);
        }
        short8 af;
        #pragma unroll
        for (int j = 0; j < 8; j++) af[j] = (short)f2bf(vals[j]);
        #pragma unroll
        for (int tp = 0; tp < 4; tp++) {
            const int t = ch * 4 + tp;
            short8 bo = *(const short8*)(Wop + ((long)(s * 16 + t) * 64 + lane) * 8);
            acc[tp] = __builtin_amdgcn_mfma_f32_16x16x32_bf16(af, bo, acc[tp], 0, 0, 0);
        }
    }

    #pragma unroll
    for (int tp = 0; tp < 4; tp++) {
        #pragma unroll
        for (int r = 0; r < 4; r++)
            out[(i0 + quad * 4 + r) * C_DIM + (ch * 4 + tp) * 16 + l15] = acc[tp][r];
    }
}

// ---------------------------------------------------------------------------
extern "C" void kernel_launch(void* const* d_in, const int* in_sizes, int n_in,
                              void* d_out, int out_size, void* d_ws, size_t ws_size,
                              hipStream_t stream)
{
    const float* query   = (const float*)d_in[0];
    const float* context = (const float*)d_in[1];
    const float* Wq      = (const float*)d_in[2];
    const float* Wk      = (const float*)d_in[3];
    const float* Wv      = (const float*)d_in[4];
    const float* Wo      = (const float*)d_in[5];
    float* out = (float*)d_out;

    char* ws = (char*)d_ws;
    unsigned short* Qb = (unsigned short*)(ws);                    // 2 MB [bh][n][32]
    unsigned short* Kb = (unsigned short*)(ws + (2 << 20));        // 2 MB [bh][n][32]
    unsigned short* Vb = (unsigned short*)(ws + (4 << 20));        // 2 MB [bh][32][n]
    unsigned short* AO = (unsigned short*)(ws + (6 << 20));        // 16 MB [8][b*n][128] bf16
    float*          Lb = (float*)(ws + (22 << 20));                // 1 MB [8][bh][n]
    unsigned short* Wp = (unsigned short*)(ws + (23 << 20));       // 256 KB packed

    wpack_kernel<<<dim3(64), dim3(256), 0, stream>>>(Wq, Wk, Wv, Wo, Wp);
    qkv_kernel<<<dim3(512), dim3(256), 0, stream>>>(query, context, Wp, Qb, Kb, Vb);
    attn_kernel<<<dim3(32 * BH * SPLITS), dim3(256), 0, stream>>>(
        Qb, Kb, Vb, AO, Lb);
    outproj_kernel<<<dim3(512), dim3(256), 0, stream>>>(AO, Lb, Wp, out);
}

// Round 5
// 130.028 us; speedup vs baseline: 1.1386x; 1.1386x over previous
//
#include <hip/hip_runtime.h>
#include <hip/hip_bf16.h>
#include <math.h>

// Problem constants (fixed by reference: b=2, h=w=64, dim=256, attn_dim=128, HEAD=4)
#define N_TOK 4096
#define C_DIM 256
#define A_DIM 128
#define HEADS 4
#define HD    32
#define NBAT  2
#define BH    (NBAT * HEADS)

// (1/sqrt(32)) * log2(e) — folded into Wq at pack time
#define SCALE_LOG2E 0.25503521f

#define SPLITS 8
#define KEYS_PER_SPLIT (N_TOK / SPLITS)

// padded LDS strides (shorts): row-start bank spread -> <=2-way conflicts (free)
#define KS 40
#define VS 72

typedef __attribute__((ext_vector_type(8))) short short8;   // 8 bf16 frag
typedef __attribute__((ext_vector_type(4))) short short4_t; // 4 bf16
typedef __attribute__((ext_vector_type(4))) float floatx4;  // MFMA C/D frag

__device__ __forceinline__ unsigned short f2bf(float f) {   // RNE
    unsigned int u = __float_as_uint(f);
    u = (u + 0x7fffu + ((u >> 16) & 1u)) >> 16;
    return (unsigned short)u;
}
__device__ __forceinline__ float bf2f(unsigned short u) {
    return __uint_as_float((unsigned int)u << 16);
}
// pack two positive floats to bf16x2 (round-half-up), lo = a, hi = b.
// NOTE (R4 post-mortem): the v_cvt_pk_bf16_f32 inline-asm replacement FAILED
// correctness (absmax 5.7e-2) — operand-half mapping / rounding semantics
// differ from this verified bit-op pack. Do not reuse without a HW probe.
__device__ __forceinline__ unsigned int pack2(float a, float b) {
    unsigned int lo = (__float_as_uint(a) + 0x8000u) >> 16;
    unsigned int hi = (__float_as_uint(b) + 0x8000u) & 0xffff0000u;
    return hi | lo;
}

// ---------------------------------------------------------------------------
// In-register quad transpose of packed bf16 key-pairs (verified R3: absmax
// 1.95e-3). Input per lane (quad q):
//   a0 = keys(4q,4q+1), a1 = keys(4q+2,4q+3)          [key-frag 0..15]
//   a2 = keys(16+4q,..), a3 = keys(16+4q+2,..)        [key-frag 16..31]
// Output: PV A-frag — lane holds keys 8q..8q+7 as 4 packed words.
// ---------------------------------------------------------------------------
__device__ __forceinline__ short8 quad_xpose(unsigned int a0, unsigned int a1,
                                             unsigned int a2, unsigned int a3,
                                             int lane)
{
    union { unsigned int u[4]; short8 s; } cv;
#if __has_builtin(__builtin_amdgcn_permlane32_swap) && __has_builtin(__builtin_amdgcn_permlane16_swap)
    (void)lane;
    auto s0 = __builtin_amdgcn_permlane32_swap(a0, a2, false, false);
    auto s1 = __builtin_amdgcn_permlane32_swap(a1, a3, false, false);
    auto t0 = __builtin_amdgcn_permlane16_swap(s0[0], s0[1], false, false);
    auto t1 = __builtin_amdgcn_permlane16_swap(s1[0], s1[1], false, false);
    cv.u[0] = t0[0]; cv.u[1] = t1[0]; cv.u[2] = t0[1]; cv.u[3] = t1[1];
#else
    // Fallback: shfl_xor(32) for the half swap, ds_swizzle xor-16 for quads.
    const int hi32 = (lane >> 5) & 1;
    const int u16  = (lane >> 4) & 1;
    unsigned int x0 = __shfl_xor(a2, 32), x2 = __shfl_xor(a0, 32);
    unsigned int r0 = hi32 ? x0 : a0;
    unsigned int r1 = hi32 ? a2 : x2;
    unsigned int y0 = __shfl_xor(a3, 32), y2 = __shfl_xor(a1, 32);
    unsigned int r0b = hi32 ? y0 : a1;
    unsigned int r1b = hi32 ? a3 : y2;
    unsigned int w0 = (unsigned int)__builtin_amdgcn_ds_swizzle((int)r1, 0x401F);
    unsigned int w1 = (unsigned int)__builtin_amdgcn_ds_swizzle((int)r0, 0x401F);
    unsigned int w2 = (unsigned int)__builtin_amdgcn_ds_swizzle((int)r1b, 0x401F);
    unsigned int w3 = (unsigned int)__builtin_amdgcn_ds_swizzle((int)r0b, 0x401F);
    cv.u[0] = u16 ? w0 : r0;
    cv.u[1] = u16 ? w2 : r0b;
    cv.u[2] = u16 ? r1 : w1;
    cv.u[3] = u16 ? r1b : w3;
#endif
    return cv.s;
}

// ---------------------------------------------------------------------------
// K0: pack weights fp32 -> bf16 in B-fragment order.
// Layout: Wp[wid][step s][tile t][lane][j]  (wid: 0=Wq(scaled) 1=Wk 2=Wv 3=Wo)
// ---------------------------------------------------------------------------
__global__ __launch_bounds__(256) void wpack_kernel(
    const float* __restrict__ Wq, const float* __restrict__ Wk,
    const float* __restrict__ Wv, const float* __restrict__ Wo,
    unsigned short* __restrict__ Wp)
{
    const int chunk = blockIdx.x * 256 + threadIdx.x;  // [0, 16384): 8 shorts each
    const int wid = chunk >> 12;
    const int c = chunk & 4095;
    const int lane = c & 63, quad = lane >> 4, l15 = lane & 15;
    short8 v;
    if (wid < 3) {
        const int s = c >> 9, t = (c >> 6) & 7;
        const float* W = (wid == 0) ? Wq : ((wid == 1) ? Wk : Wv);
        const float scale = (wid == 0) ? SCALE_LOG2E : 1.0f;
        const int src = (s * 32 + quad * 8) * A_DIM + t * 16 + l15;
        #pragma unroll
        for (int j = 0; j < 8; j++) v[j] = (short)f2bf(W[src + j * A_DIM] * scale);
    } else {
        const int s = c >> 10, t = (c >> 6) & 15;
        const int src = (s * 32 + quad * 8) * C_DIM + t * 16 + l15;
        #pragma unroll
        for (int j = 0; j < 8; j++) v[j] = (short)f2bf(Wo[src + j * C_DIM]);
    }
    *(short8*)(Wp + (long)chunk * 8) = v;
}

// ---------------------------------------------------------------------------
// K1: QKV projection via MFMA. 512 blocks x 4 waves (unchanged).
// ---------------------------------------------------------------------------
__global__ __launch_bounds__(256) void qkv_kernel(
    const float* __restrict__ query, const float* __restrict__ context,
    const unsigned short* __restrict__ Wp,
    unsigned short* __restrict__ Qb, unsigned short* __restrict__ Kb,
    unsigned short* __restrict__ Vb)
{
    __shared__ __align__(16) unsigned short V_lds[128 * 18];  // [col][tok16+pad] 4.5KB

    const int tid = threadIdx.x;
    const int w = tid >> 6, lane = tid & 63;
    const int quad = lane >> 4, l15 = lane & 15;
    const int ch = w;                      // col quarter (32 cols)
    const long i0 = (long)blockIdx.x * 16;
    const long row = i0 + l15;

    const unsigned short* Wqp = Wp;
    const unsigned short* Wkp = Wp + 32768;
    const unsigned short* Wvp = Wp + 65536;

    floatx4 aQ[2] = {}, aK[2] = {}, aV[2] = {};

    for (int s = 0; s < 8; s++) {
        const float* qp = query + row * C_DIM + s * 32 + quad * 8;
        const float* cp = context + row * C_DIM + s * 32 + quad * 8;
        floatx4 q0 = *(const floatx4*)qp, q1 = *(const floatx4*)(qp + 4);
        floatx4 c0 = *(const floatx4*)cp, c1 = *(const floatx4*)(cp + 4);
        short8 aq, ac;
        #pragma unroll
        for (int j = 0; j < 4; j++) {
            aq[j] = (short)f2bf(q0[j]); aq[4 + j] = (short)f2bf(q1[j]);
            ac[j] = (short)f2bf(c0[j]); ac[4 + j] = (short)f2bf(c1[j]);
        }
        #pragma unroll
        for (int tp = 0; tp < 2; tp++) {
            const long fo = ((long)(s * 8 + ch * 2 + tp) * 64 + lane) * 8;
            short8 bq = *(const short8*)(Wqp + fo);
            short8 bk = *(const short8*)(Wkp + fo);
            short8 bv = *(const short8*)(Wvp + fo);
            aQ[tp] = __builtin_amdgcn_mfma_f32_16x16x32_bf16(aq, bq, aQ[tp], 0, 0, 0);
            aK[tp] = __builtin_amdgcn_mfma_f32_16x16x32_bf16(ac, bk, aK[tp], 0, 0, 0);
            aV[tp] = __builtin_amdgcn_mfma_f32_16x16x32_bf16(ac, bv, aV[tp], 0, 0, 0);
        }
    }

    const long b = i0 >> 12;
    const long n0 = i0 & (N_TOK - 1);
    const long nbase = n0 + quad * 4;
    #pragma unroll
    for (int tp = 0; tp < 2; tp++) {
        const int col = ch * 32 + tp * 16 + l15;
        const int h = col >> 5, d = col & 31;
        unsigned short* qdst = Qb + ((b * HEADS + h) * N_TOK + nbase) * HD + d;
        unsigned short* kdst = Kb + ((b * HEADS + h) * N_TOK + nbase) * HD + d;
        #pragma unroll
        for (int r = 0; r < 4; r++) {
            qdst[r * HD] = f2bf(aQ[tp][r]);
            kdst[r * HD] = f2bf(aK[tp][r]);
        }
        short4_t pv;
        #pragma unroll
        for (int r = 0; r < 4; r++) pv[r] = (short)f2bf(aV[tp][r]);
        *(short4_t*)&V_lds[col * 18 + quad * 4] = pv;
    }
    __syncthreads();

    {   // cooperative V^T write-out: 128 cols x 16 tokens; 16B chunks
        const int col = tid >> 1, seg = tid & 1;
        const int h = col >> 5, d = col & 31;
        unsigned short* dst = Vb + ((b * HEADS + h) * HD + d) * N_TOK + n0 + seg * 8;
        *(short8*)dst = *(const short8*)&V_lds[col * 18 + seg * 8];
    }
}

// ---------------------------------------------------------------------------
// K2: flash attention, no-max softmax, split-K=8, S^T formulation. HYBRID:
//  - Cooperative K/V staging in LDS (2 loads/thread/tile, padded strides),
//    DOUBLE-BUFFERED -> ONE barrier per tile (was 2), depth-2 global prefetch.
//  - P^T -> P transpose fully in-register (quad_xpose, verified R3): no P_lds,
//    no lgkmcnt chain on the softmax->PV critical path. LDS 30KB -> 19KB.
//  - P packing via the VERIFIED pack2 bit-ops (cvtpk asm failed R4).
//  - Denominator: per-lane column sums, quad-reduced at the end.
// ---------------------------------------------------------------------------
__global__ __launch_bounds__(256, 4) void attn_kernel(
    const unsigned short* __restrict__ Qb, const unsigned short* __restrict__ Kb,
    const unsigned short* __restrict__ Vb,
    unsigned short* __restrict__ AO, float* __restrict__ Lbuf)
{
    __shared__ __align__(16) unsigned short K_lds[2][64 * KS];   // 2 x 5 KB
    __shared__ __align__(16) unsigned short V_lds[2][HD * VS];   // 2 x 4.5 KB

    const int tid  = threadIdx.x;
    const int w    = tid >> 6;
    const int lane = tid & 63;
    const int quad = lane >> 4;
    const int l15  = lane & 15;

    // XCD swizzle: blocks with equal (bh,z) share L%8 -> same XCD L2.
    const int L  = blockIdx.x;
    const int g  = (L & 7) + 8 * ((L >> 3) >> 5);  // group 0..63
    const int qb = (L >> 3) & 31;                  // q-block 0..31
    const int bh = g & 7;
    const int z  = g >> 3;
    const int i0 = qb * 128 + w * 32;

    const unsigned short* Qh = Qb + (long)bh * N_TOK * HD;
    const unsigned short* Kh = Kb + (long)bh * N_TOK * HD;
    const unsigned short* Vh = Vb + (long)bh * HD * N_TOK;

    const short8 qfA = *(const short8*)(Qh + (long)(i0 + l15) * HD + quad * 8);
    const short8 qfB = *(const short8*)(Qh + (long)(i0 + 16 + l15) * HD + quad * 8);

    floatx4 accA0 = {0.f,0.f,0.f,0.f}, accA1 = {0.f,0.f,0.f,0.f};
    floatx4 accB0 = {0.f,0.f,0.f,0.f}, accB1 = {0.f,0.f,0.f,0.f};
    float lAc = 0.f, lBc = 0.f;   // denom partial for query l15 (this lane's col)

    const int  kst = (tid >> 2) * KS + (tid & 3) * 8;   // K stage: row tid>>2, 8-short chunk
    const int  vst = (tid >> 3) * VS + (tid & 7) * 8;   // V stage: dim tid>>3
    const long vgl = (long)(tid >> 3) * N_TOK + (tid & 7) * 8;

    const int j_lo = z * KEYS_PER_SPLIT;
    const int nt   = KEYS_PER_SPLIT / 64;               // 8 tiles

    // prologue: stage tile 0, prefetch tile 1 into registers
    short8 kreg = *(const short8*)(Kh + (long)j_lo * HD + tid * 8);
    short8 vreg = *(const short8*)(Vh + vgl + j_lo);
    *(short8*)&K_lds[0][kst] = kreg;
    *(short8*)&V_lds[0][vst] = vreg;
    kreg = *(const short8*)(Kh + (long)(j_lo + 64) * HD + tid * 8);
    vreg = *(const short8*)(Vh + vgl + j_lo + 64);
    __syncthreads();

    #pragma unroll 1
    for (int t = 0; t < nt; ++t) {
        const int cur = t & 1;

        #pragma unroll
        for (int sub = 0; sub < 2; sub++) {
            const int jb = sub * 32;
            short8 kf0 = *(short8*)&K_lds[cur][(jb + l15) * KS + quad * 8];
            short8 kf1 = *(short8*)&K_lds[cur][(jb + 16 + l15) * KS + quad * 8];
            const floatx4 zf = {0.f,0.f,0.f,0.f};
            // S^T = K · Q^T : C rows = keys, cols = queries
            floatx4 sA0 = __builtin_amdgcn_mfma_f32_16x16x32_bf16(kf0, qfA, zf, 0, 0, 0);
            floatx4 sA1 = __builtin_amdgcn_mfma_f32_16x16x32_bf16(kf1, qfA, zf, 0, 0, 0);
            floatx4 sB0 = __builtin_amdgcn_mfma_f32_16x16x32_bf16(kf0, qfB, zf, 0, 0, 0);
            floatx4 sB1 = __builtin_amdgcn_mfma_f32_16x16x32_bf16(kf1, qfB, zf, 0, 0, 0);

            floatx4 pA0, pA1, pB0, pB1;
            #pragma unroll
            for (int r = 0; r < 4; r++) {
                pA0[r] = __builtin_amdgcn_exp2f(sA0[r]);
                pA1[r] = __builtin_amdgcn_exp2f(sA1[r]);
                pB0[r] = __builtin_amdgcn_exp2f(sB0[r]);
                pB1[r] = __builtin_amdgcn_exp2f(sB1[r]);
                lAc += pA0[r] + pA1[r];
                lBc += pB0[r] + pB1[r];
            }

            // pack key pairs (verified pack2) and transpose quads in-register
            short8 pfA = quad_xpose(pack2(pA0[0], pA0[1]), pack2(pA0[2], pA0[3]),
                                    pack2(pA1[0], pA1[1]), pack2(pA1[2], pA1[3]), lane);
            short8 pfB = quad_xpose(pack2(pB0[0], pB0[1]), pack2(pB0[2], pB0[3]),
                                    pack2(pB1[0], pB1[1]), pack2(pB1[2], pB1[3]), lane);

            short8 vf0 = *(short8*)&V_lds[cur][l15 * VS + jb + quad * 8];
            short8 vf1 = *(short8*)&V_lds[cur][(16 + l15) * VS + jb + quad * 8];
            accA0 = __builtin_amdgcn_mfma_f32_16x16x32_bf16(pfA, vf0, accA0, 0, 0, 0);
            accA1 = __builtin_amdgcn_mfma_f32_16x16x32_bf16(pfA, vf1, accA1, 0, 0, 0);
            accB0 = __builtin_amdgcn_mfma_f32_16x16x32_bf16(pfB, vf0, accB0, 0, 0, 0);
            accB1 = __builtin_amdgcn_mfma_f32_16x16x32_bf16(pfB, vf1, accB1, 0, 0, 0);
        }

        if (t + 1 < nt) {
            // stage tile t+1 (regs loaded 1 tile ago -> vmcnt long satisfied)
            *(short8*)&K_lds[cur ^ 1][kst] = kreg;
            *(short8*)&V_lds[cur ^ 1][vst] = vreg;
            if (t + 2 < nt) {   // depth-2 prefetch
                kreg = *(const short8*)(Kh + (long)(j_lo + (t + 2) * 64) * HD + tid * 8);
                vreg = *(const short8*)(Vh + vgl + j_lo + (t + 2) * 64);
            }
            __syncthreads();   // one barrier per tile: orders write(buf^1) vs read
        }
    }

    // denom: sum the 4 quads holding the same query column
    lAc += __shfl_xor(lAc, 16); lAc += __shfl_xor(lAc, 32);
    lBc += __shfl_xor(lBc, 16); lBc += __shfl_xor(lBc, 32);

    const int b = bh >> 2, h = bh & 3;
    unsigned short* AOz = AO + (long)z * (NBAT * N_TOK * A_DIM);
    float* Lz = Lbuf + (long)z * (BH * N_TOK);
    if (quad == 0) {   // one lane per query writes the denominator
        Lz[(long)bh * N_TOK + i0 + l15]      = lAc;
        Lz[(long)bh * N_TOK + i0 + 16 + l15] = lBc;
    }
    #pragma unroll
    for (int r = 0; r < 4; r++) {
        // O C-frags: rows = queries quad*4+r; fetch that query's denom by shfl
        const float invA = 1.0f / __shfl(lAc, quad * 4 + r);
        const float invB = 1.0f / __shfl(lBc, quad * 4 + r);
        const long rowA = (long)b * N_TOK + i0 + quad * 4 + r;
        const long rowB = rowA + 16;
        AOz[rowA * A_DIM + h * HD + l15]      = f2bf(accA0[r] * invA);
        AOz[rowA * A_DIM + h * HD + 16 + l15] = f2bf(accA1[r] * invA);
        AOz[rowB * A_DIM + h * HD + l15]      = f2bf(accB0[r] * invB);
        AOz[rowB * A_DIM + h * HD + 16 + l15] = f2bf(accB1[r] * invB);
    }
}

// ---------------------------------------------------------------------------
// K3: split-K combine + out-projection via MFMA. 512 blocks x 4 waves
// (unchanged).
// ---------------------------------------------------------------------------
__global__ __launch_bounds__(256) void outproj_kernel(
    const unsigned short* __restrict__ AO, const float* __restrict__ Lbuf,
    const unsigned short* __restrict__ Wp, float* __restrict__ out)
{
    const int tid = threadIdx.x;
    const int w = tid >> 6, lane = tid & 63;
    const int quad = lane >> 4, l15 = lane & 15;
    const int ch = w;                       // col quarter (64 cols)
    const long i0 = (long)blockIdx.x * 16;
    const long row = i0 + l15;
    const int b = (int)(row >> 12);
    const int n = (int)(row & (N_TOK - 1));
    const unsigned short* Wop = Wp + 98304;

    floatx4 acc[4] = {};

    #pragma unroll
    for (int s = 0; s < 4; s++) {   // k-step == head s (32-aligned)
        float lz[SPLITS], lsum = 0.f;
        #pragma unroll
        for (int z = 0; z < SPLITS; z++) {
            lz[z] = Lbuf[(long)z * (BH * N_TOK) + (long)(b * HEADS + s) * N_TOK + n];
            lsum += lz[z];
        }
        const float inv = 1.0f / lsum;
        float vals[8] = {};
        #pragma unroll
        for (int z = 0; z < SPLITS; z++) {
            short8 az = *(const short8*)(AO + (long)z * (NBAT * N_TOK * A_DIM) +
                                         row * A_DIM + s * 32 + quad * 8);
            const float wz = lz[z] * inv;
            #pragma unroll
            for (int j = 0; j < 8; j++) vals[j] += wz * bf2f((unsigned short)az[j]);
        }
        short8 af;
        #pragma unroll
        for (int j = 0; j < 8; j++) af[j] = (short)f2bf(vals[j]);
        #pragma unroll
        for (int tp = 0; tp < 4; tp++) {
            const int t = ch * 4 + tp;
            short8 bo = *(const short8*)(Wop + ((long)(s * 16 + t) * 64 + lane) * 8);
            acc[tp] = __builtin_amdgcn_mfma_f32_16x16x32_bf16(af, bo, acc[tp], 0, 0, 0);
        }
    }

    #pragma unroll
    for (int tp = 0; tp < 4; tp++) {
        #pragma unroll
        for (int r = 0; r < 4; r++)
            out[(i0 + quad * 4 + r) * C_DIM + (ch * 4 + tp) * 16 + l15] = acc[tp][r];
    }
}

// ---------------------------------------------------------------------------
extern "C" void kernel_launch(void* const* d_in, const int* in_sizes, int n_in,
                              void* d_out, int out_size, void* d_ws, size_t ws_size,
                              hipStream_t stream)
{
    const float* query   = (const float*)d_in[0];
    const float* context = (const float*)d_in[1];
    const float* Wq      = (const float*)d_in[2];
    const float* Wk      = (const float*)d_in[3];
    const float* Wv      = (const float*)d_in[4];
    const float* Wo      = (const float*)d_in[5];
    float* out = (float*)d_out;

    char* ws = (char*)d_ws;
    unsigned short* Qb = (unsigned short*)(ws);                    // 2 MB [bh][n][32]
    unsigned short* Kb = (unsigned short*)(ws + (2 << 20));        // 2 MB [bh][n][32]
    unsigned short* Vb = (unsigned short*)(ws + (4 << 20));        // 2 MB [bh][32][n]
    unsigned short* AO = (unsigned short*)(ws + (6 << 20));        // 16 MB [8][b*n][128] bf16
    float*          Lb = (float*)(ws + (22 << 20));                // 1 MB [8][bh][n]
    unsigned short* Wp = (unsigned short*)(ws + (23 << 20));       // 256 KB packed

    wpack_kernel<<<dim3(64), dim3(256), 0, stream>>>(Wq, Wk, Wv, Wo, Wp);
    qkv_kernel<<<dim3(512), dim3(256), 0, stream>>>(query, context, Wp, Qb, Kb, Vb);
    attn_kernel<<<dim3(32 * BH * SPLITS), dim3(256), 0, stream>>>(
        Qb, Kb, Vb, AO, Lb);
    outproj_kernel<<<dim3(512), dim3(256), 0, stream>>>(AO, Lb, Wp, out);
}

// Round 7
// 123.265 us; speedup vs baseline: 1.2011x; 1.0549x over previous
//
#include <hip/hip_runtime.h>
#include <hip/hip_bf16.h>
#include <math.h>

// Problem constants (fixed by reference: b=2, h=w=64, dim=256, attn_dim=128, HEAD=4)
#define N_TOK 4096
#define C_DIM 256
#define A_DIM 128
#define HEADS 4
#define HD    32
#define NBAT  2
#define BH    (NBAT * HEADS)

// (1/sqrt(32)) * log2(e) — folded into Wq at pack time
#define SCALE_LOG2E 0.25503521f

#define SPLITS 4
#define KEYS_PER_SPLIT (N_TOK / SPLITS)

// padded LDS strides (shorts): row-start bank spread -> <=2-way conflicts (free)
#define KS 40
#define VS 72

typedef __attribute__((ext_vector_type(8))) short short8;   // 8 bf16 frag
typedef __attribute__((ext_vector_type(4))) short short4_t; // 4 bf16
typedef __attribute__((ext_vector_type(4))) float floatx4;  // MFMA C/D frag

__device__ __forceinline__ unsigned short f2bf(float f) {   // RNE
    unsigned int u = __float_as_uint(f);
    u = (u + 0x7fffu + ((u >> 16) & 1u)) >> 16;
    return (unsigned short)u;
}
__device__ __forceinline__ float bf2f(unsigned short u) {
    return __uint_as_float((unsigned int)u << 16);
}
// pack two positive floats to bf16x2 (round-half-up), lo = a, hi = b.
// NOTE (R4 post-mortem): the v_cvt_pk_bf16_f32 inline-asm replacement FAILED
// correctness (absmax 5.7e-2) — do not reuse without a HW semantics probe.
__device__ __forceinline__ unsigned int pack2(float a, float b) {
    unsigned int lo = (__float_as_uint(a) + 0x8000u) >> 16;
    unsigned int hi = (__float_as_uint(b) + 0x8000u) & 0xffff0000u;
    return hi | lo;
}

// ---------------------------------------------------------------------------
// In-register quad transpose of packed bf16 key-pairs (verified R3/R5).
// Input per lane (quad q):
//   a0 = keys(4q,4q+1), a1 = keys(4q+2,4q+3)          [key-frag 0..15]
//   a2 = keys(16+4q,..), a3 = keys(16+4q+2,..)        [key-frag 16..31]
// Output: PV A-frag — lane holds keys 8q..8q+7 as 4 packed words.
// ---------------------------------------------------------------------------
__device__ __forceinline__ short8 quad_xpose(unsigned int a0, unsigned int a1,
                                             unsigned int a2, unsigned int a3,
                                             int lane)
{
    union { unsigned int u[4]; short8 s; } cv;
#if __has_builtin(__builtin_amdgcn_permlane32_swap) && __has_builtin(__builtin_amdgcn_permlane16_swap)
    (void)lane;
    auto s0 = __builtin_amdgcn_permlane32_swap(a0, a2, false, false);
    auto s1 = __builtin_amdgcn_permlane32_swap(a1, a3, false, false);
    auto t0 = __builtin_amdgcn_permlane16_swap(s0[0], s0[1], false, false);
    auto t1 = __builtin_amdgcn_permlane16_swap(s1[0], s1[1], false, false);
    cv.u[0] = t0[0]; cv.u[1] = t1[0]; cv.u[2] = t0[1]; cv.u[3] = t1[1];
#else
    // Fallback: shfl_xor(32) for the half swap, ds_swizzle xor-16 for quads.
    const int hi32 = (lane >> 5) & 1;
    const int u16  = (lane >> 4) & 1;
    unsigned int x0 = __shfl_xor(a2, 32), x2 = __shfl_xor(a0, 32);
    unsigned int r0 = hi32 ? x0 : a0;
    unsigned int r1 = hi32 ? a2 : x2;
    unsigned int y0 = __shfl_xor(a3, 32), y2 = __shfl_xor(a1, 32);
    unsigned int r0b = hi32 ? y0 : a1;
    unsigned int r1b = hi32 ? a3 : y2;
    unsigned int w0 = (unsigned int)__builtin_amdgcn_ds_swizzle((int)r1, 0x401F);
    unsigned int w1 = (unsigned int)__builtin_amdgcn_ds_swizzle((int)r0, 0x401F);
    unsigned int w2 = (unsigned int)__builtin_amdgcn_ds_swizzle((int)r1b, 0x401F);
    unsigned int w3 = (unsigned int)__builtin_amdgcn_ds_swizzle((int)r0b, 0x401F);
    cv.u[0] = u16 ? w0 : r0;
    cv.u[1] = u16 ? w2 : r0b;
    cv.u[2] = u16 ? r1 : w1;
    cv.u[3] = u16 ? r1b : w3;
#endif
    return cv.s;
}

// ---------------------------------------------------------------------------
// K0: pack weights fp32 -> bf16 in B-fragment order.
// Layout: Wp[wid][step s][tile t][lane][j]  (wid: 0=Wq(scaled) 1=Wk 2=Wv 3=Wo)
// ---------------------------------------------------------------------------
__global__ __launch_bounds__(256) void wpack_kernel(
    const float* __restrict__ Wq, const float* __restrict__ Wk,
    const float* __restrict__ Wv, const float* __restrict__ Wo,
    unsigned short* __restrict__ Wp)
{
    const int chunk = blockIdx.x * 256 + threadIdx.x;  // [0, 16384): 8 shorts each
    const int wid = chunk >> 12;
    const int c = chunk & 4095;
    const int lane = c & 63, quad = lane >> 4, l15 = lane & 15;
    short8 v;
    if (wid < 3) {
        const int s = c >> 9, t = (c >> 6) & 7;
        const float* W = (wid == 0) ? Wq : ((wid == 1) ? Wk : Wv);
        const float scale = (wid == 0) ? SCALE_LOG2E : 1.0f;
        const int src = (s * 32 + quad * 8) * A_DIM + t * 16 + l15;
        #pragma unroll
        for (int j = 0; j < 8; j++) v[j] = (short)f2bf(W[src + j * A_DIM] * scale);
    } else {
        const int s = c >> 10, t = (c >> 6) & 15;
        const int src = (s * 32 + quad * 8) * C_DIM + t * 16 + l15;
        #pragma unroll
        for (int j = 0; j < 8; j++) v[j] = (short)f2bf(Wo[src + j * C_DIM]);
    }
    *(short8*)(Wp + (long)chunk * 8) = v;
}

// ---------------------------------------------------------------------------
// K1: QKV projection via MFMA. 512 blocks x 4 waves (unchanged).
// ---------------------------------------------------------------------------
__global__ __launch_bounds__(256) void qkv_kernel(
    const float* __restrict__ query, const float* __restrict__ context,
    const unsigned short* __restrict__ Wp,
    unsigned short* __restrict__ Qb, unsigned short* __restrict__ Kb,
    unsigned short* __restrict__ Vb)
{
    __shared__ __align__(16) unsigned short V_lds[128 * 18];  // [col][tok16+pad] 4.5KB

    const int tid = threadIdx.x;
    const int w = tid >> 6, lane = tid & 63;
    const int quad = lane >> 4, l15 = lane & 15;
    const int ch = w;                      // col quarter (32 cols)
    const long i0 = (long)blockIdx.x * 16;
    const long row = i0 + l15;

    const unsigned short* Wqp = Wp;
    const unsigned short* Wkp = Wp + 32768;
    const unsigned short* Wvp = Wp + 65536;

    floatx4 aQ[2] = {}, aK[2] = {}, aV[2] = {};

    for (int s = 0; s < 8; s++) {
        const float* qp = query + row * C_DIM + s * 32 + quad * 8;
        const float* cp = context + row * C_DIM + s * 32 + quad * 8;
        floatx4 q0 = *(const floatx4*)qp, q1 = *(const floatx4*)(qp + 4);
        floatx4 c0 = *(const floatx4*)cp, c1 = *(const floatx4*)(cp + 4);
        short8 aq, ac;
        #pragma unroll
        for (int j = 0; j < 4; j++) {
            aq[j] = (short)f2bf(q0[j]); aq[4 + j] = (short)f2bf(q1[j]);
            ac[j] = (short)f2bf(c0[j]); ac[4 + j] = (short)f2bf(c1[j]);
        }
        #pragma unroll
        for (int tp = 0; tp < 2; tp++) {
            const long fo = ((long)(s * 8 + ch * 2 + tp) * 64 + lane) * 8;
            short8 bq = *(const short8*)(Wqp + fo);
            short8 bk = *(const short8*)(Wkp + fo);
            short8 bv = *(const short8*)(Wvp + fo);
            aQ[tp] = __builtin_amdgcn_mfma_f32_16x16x32_bf16(aq, bq, aQ[tp], 0, 0, 0);
            aK[tp] = __builtin_amdgcn_mfma_f32_16x16x32_bf16(ac, bk, aK[tp], 0, 0, 0);
            aV[tp] = __builtin_amdgcn_mfma_f32_16x16x32_bf16(ac, bv, aV[tp], 0, 0, 0);
        }
    }

    const long b = i0 >> 12;
    const long n0 = i0 & (N_TOK - 1);
    const long nbase = n0 + quad * 4;
    #pragma unroll
    for (int tp = 0; tp < 2; tp++) {
        const int col = ch * 32 + tp * 16 + l15;
        const int h = col >> 5, d = col & 31;
        unsigned short* qdst = Qb + ((b * HEADS + h) * N_TOK + nbase) * HD + d;
        unsigned short* kdst = Kb + ((b * HEADS + h) * N_TOK + nbase) * HD + d;
        #pragma unroll
        for (int r = 0; r < 4; r++) {
            qdst[r * HD] = f2bf(aQ[tp][r]);
            kdst[r * HD] = f2bf(aK[tp][r]);
        }
        short4_t pv;
        #pragma unroll
        for (int r = 0; r < 4; r++) pv[r] = (short)f2bf(aV[tp][r]);
        *(short4_t*)&V_lds[col * 18 + quad * 4] = pv;
    }
    __syncthreads();

    {   // cooperative V^T write-out: 128 cols x 16 tokens; 16B chunks
        const int col = tid >> 1, seg = tid & 1;
        const int h = col >> 5, d = col & 31;
        unsigned short* dst = Vb + ((b * HEADS + h) * HD + d) * N_TOK + n0 + seg * 8;
        *(short8*)dst = *(const short8*)&V_lds[col * 18 + seg * 8];
    }
}

// ---------------------------------------------------------------------------
// K2: flash attention, no-max softmax, split-K=4, S^T formulation.
//  - Cooperative K/V staging in LDS, double-buffered, 1 barrier/tile,
//    depth-2 global prefetch (verified R5).
//  - P^T -> P transpose fully in-register (quad_xpose, verified R3/R5).
//  - NEW: denominator via MFMA ones-column — den = mfma(pf, ones, den)
//    replicates row-sum(P) across the 16 output cols. Removes all 32
//    denominator v_add_f32 per tile per lane from the VALU pipe and the
//    epilogue shfl-reduce entirely; denominator is self-consistent with
//    the bf16-rounded P used in the PV numerator.
// ---------------------------------------------------------------------------
__global__ __launch_bounds__(256, 4) void attn_kernel(
    const unsigned short* __restrict__ Qb, const unsigned short* __restrict__ Kb,
    const unsigned short* __restrict__ Vb,
    unsigned short* __restrict__ AO, float* __restrict__ Lbuf)
{
    __shared__ __align__(16) unsigned short K_lds[2][64 * KS];   // 2 x 5 KB
    __shared__ __align__(16) unsigned short V_lds[2][HD * VS];   // 2 x 4.5 KB

    const int tid  = threadIdx.x;
    const int w    = tid >> 6;
    const int lane = tid & 63;
    const int quad = lane >> 4;
    const int l15  = lane & 15;

    // XCD swizzle: blocks with equal (bh,z) share L%8 -> same XCD L2.
    const int L  = blockIdx.x;
    const int g  = (L & 7) + 8 * ((L >> 3) >> 5);  // group 0..31
    const int qb = (L >> 3) & 31;                  // q-block 0..31
    const int bh = g & 7;
    const int z  = g >> 3;                         // 0..SPLITS-1
    const int i0 = qb * 128 + w * 32;

    const unsigned short* Qh = Qb + (long)bh * N_TOK * HD;
    const unsigned short* Kh = Kb + (long)bh * N_TOK * HD;
    const unsigned short* Vh = Vb + (long)bh * HD * N_TOK;

    const short8 qfA = *(const short8*)(Qh + (long)(i0 + l15) * HD + quad * 8);
    const short8 qfB = *(const short8*)(Qh + (long)(i0 + 16 + l15) * HD + quad * 8);

    // all-ones bf16 B-fragment for the denominator MFMA
    const short8 onesf = {(short)0x3F80, (short)0x3F80, (short)0x3F80, (short)0x3F80,
                          (short)0x3F80, (short)0x3F80, (short)0x3F80, (short)0x3F80};

    floatx4 accA0 = {0.f,0.f,0.f,0.f}, accA1 = {0.f,0.f,0.f,0.f};
    floatx4 accB0 = {0.f,0.f,0.f,0.f}, accB1 = {0.f,0.f,0.f,0.f};
    floatx4 denA  = {0.f,0.f,0.f,0.f}, denB  = {0.f,0.f,0.f,0.f};

    const int  kst = (tid >> 2) * KS + (tid & 3) * 8;   // K stage: row tid>>2
    const int  vst = (tid >> 3) * VS + (tid & 7) * 8;   // V stage: dim tid>>3
    const long vgl = (long)(tid >> 3) * N_TOK + (tid & 7) * 8;

    const int j_lo = z * KEYS_PER_SPLIT;
    const int nt   = KEYS_PER_SPLIT / 64;               // 16 tiles

    // prologue: stage tile 0, prefetch tile 1 into registers
    short8 kreg = *(const short8*)(Kh + (long)j_lo * HD + tid * 8);
    short8 vreg = *(const short8*)(Vh + vgl + j_lo);
    *(short8*)&K_lds[0][kst] = kreg;
    *(short8*)&V_lds[0][vst] = vreg;
    kreg = *(const short8*)(Kh + (long)(j_lo + 64) * HD + tid * 8);
    vreg = *(const short8*)(Vh + vgl + j_lo + 64);
    __syncthreads();

    #pragma unroll 1
    for (int t = 0; t < nt; ++t) {
        const int cur = t & 1;

        #pragma unroll
        for (int sub = 0; sub < 2; sub++) {
            const int jb = sub * 32;
            short8 kf0 = *(short8*)&K_lds[cur][(jb + l15) * KS + quad * 8];
            short8 kf1 = *(short8*)&K_lds[cur][(jb + 16 + l15) * KS + quad * 8];
            const floatx4 zf = {0.f,0.f,0.f,0.f};
            // S^T = K · Q^T : C rows = keys, cols = queries
            floatx4 sA0 = __builtin_amdgcn_mfma_f32_16x16x32_bf16(kf0, qfA, zf, 0, 0, 0);
            floatx4 sA1 = __builtin_amdgcn_mfma_f32_16x16x32_bf16(kf1, qfA, zf, 0, 0, 0);
            floatx4 sB0 = __builtin_amdgcn_mfma_f32_16x16x32_bf16(kf0, qfB, zf, 0, 0, 0);
            floatx4 sB1 = __builtin_amdgcn_mfma_f32_16x16x32_bf16(kf1, qfB, zf, 0, 0, 0);

            floatx4 pA0, pA1, pB0, pB1;
            #pragma unroll
            for (int r = 0; r < 4; r++) {
                pA0[r] = __builtin_amdgcn_exp2f(sA0[r]);
                pA1[r] = __builtin_amdgcn_exp2f(sA1[r]);
                pB0[r] = __builtin_amdgcn_exp2f(sB0[r]);
                pB1[r] = __builtin_amdgcn_exp2f(sB1[r]);
            }

            // pack key pairs (verified pack2) and transpose quads in-register
            short8 pfA = quad_xpose(pack2(pA0[0], pA0[1]), pack2(pA0[2], pA0[3]),
                                    pack2(pA1[0], pA1[1]), pack2(pA1[2], pA1[3]), lane);
            short8 pfB = quad_xpose(pack2(pB0[0], pB0[1]), pack2(pB0[2], pB0[3]),
                                    pack2(pB1[0], pB1[1]), pack2(pB1[2], pB1[3]), lane);

            short8 vf0 = *(short8*)&V_lds[cur][l15 * VS + jb + quad * 8];
            short8 vf1 = *(short8*)&V_lds[cur][(16 + l15) * VS + jb + quad * 8];
            accA0 = __builtin_amdgcn_mfma_f32_16x16x32_bf16(pfA, vf0, accA0, 0, 0, 0);
            accA1 = __builtin_amdgcn_mfma_f32_16x16x32_bf16(pfA, vf1, accA1, 0, 0, 0);
            accB0 = __builtin_amdgcn_mfma_f32_16x16x32_bf16(pfB, vf0, accB0, 0, 0, 0);
            accB1 = __builtin_amdgcn_mfma_f32_16x16x32_bf16(pfB, vf1, accB1, 0, 0, 0);
            // denominator on the MFMA pipe: every output col = row-sum of P
            denA  = __builtin_amdgcn_mfma_f32_16x16x32_bf16(pfA, onesf, denA, 0, 0, 0);
            denB  = __builtin_amdgcn_mfma_f32_16x16x32_bf16(pfB, onesf, denB, 0, 0, 0);
        }

        if (t + 1 < nt) {
            // stage tile t+1 (regs loaded 1 tile ago -> vmcnt long satisfied)
            *(short8*)&K_lds[cur ^ 1][kst] = kreg;
            *(short8*)&V_lds[cur ^ 1][vst] = vreg;
            if (t + 2 < nt) {   // depth-2 prefetch
                kreg = *(const short8*)(Kh + (long)(j_lo + (t + 2) * 64) * HD + tid * 8);
                vreg = *(const short8*)(Vh + vgl + j_lo + (t + 2) * 64);
            }
            __syncthreads();   // one barrier per tile: orders write(buf^1) vs read
        }
    }

    // denA[r] holds denom(query i0+quad*4+r), replicated across the 16 l15
    // lanes of the quad — exactly the C-frag row layout the epilogue needs.
    const int b = bh >> 2, h = bh & 3;
    unsigned short* AOz = AO + (long)z * (NBAT * N_TOK * A_DIM);
    float* Lz = Lbuf + (long)z * (BH * N_TOK);
    if (l15 == 0) {   // one lane per quad writes 4+4 denominators
        #pragma unroll
        for (int r = 0; r < 4; r++) {
            Lz[(long)bh * N_TOK + i0 + quad * 4 + r]      = denA[r];
            Lz[(long)bh * N_TOK + i0 + 16 + quad * 4 + r] = denB[r];
        }
    }
    #pragma unroll
    for (int r = 0; r < 4; r++) {
        const float invA = 1.0f / denA[r];
        const float invB = 1.0f / denB[r];
        const long rowA = (long)b * N_TOK + i0 + quad * 4 + r;
        const long rowB = rowA + 16;
        AOz[rowA * A_DIM + h * HD + l15]      = f2bf(accA0[r] * invA);
        AOz[rowA * A_DIM + h * HD + 16 + l15] = f2bf(accA1[r] * invA);
        AOz[rowB * A_DIM + h * HD + l15]      = f2bf(accB0[r] * invB);
        AOz[rowB * A_DIM + h * HD + 16 + l15] = f2bf(accB1[r] * invB);
    }
}

// ---------------------------------------------------------------------------
// K3: split-K combine + out-projection via MFMA. 512 blocks x 4 waves.
// SPLITS=4 halves the combine loads/FMAs vs R5.
// ---------------------------------------------------------------------------
__global__ __launch_bounds__(256) void outproj_kernel(
    const unsigned short* __restrict__ AO, const float* __restrict__ Lbuf,
    const unsigned short* __restrict__ Wp, float* __restrict__ out)
{
    const int tid = threadIdx.x;
    const int w = tid >> 6, lane = tid & 63;
    const int quad = lane >> 4, l15 = lane & 15;
    const int ch = w;                       // col quarter (64 cols)
    const long i0 = (long)blockIdx.x * 16;
    const long row = i0 + l15;
    const int b = (int)(row >> 12);
    const int n = (int)(row & (N_TOK - 1));
    const unsigned short* Wop = Wp + 98304;

    floatx4 acc[4] = {};

    #pragma unroll
    for (int s = 0; s < 4; s++) {   // k-step == head s (32-aligned)
        float lz[SPLITS], lsum = 0.f;
        #pragma unroll
        for (int z = 0; z < SPLITS; z++) {
            lz[z] = Lbuf[(long)z * (BH * N_TOK) + (long)(b * HEADS + s) * N_TOK + n];
            lsum += lz[z];
        }
        const float inv = 1.0f / lsum;
        float vals[8] = {};
        #pragma unroll
        for (int z = 0; z < SPLITS; z++) {
            short8 az = *(const short8*)(AO + (long)z * (NBAT * N_TOK * A_DIM) +
                                         row * A_DIM + s * 32 + quad * 8);
            const float wz = lz[z] * inv;
            #pragma unroll
            for (int j = 0; j < 8; j++) vals[j] += wz * bf2f((unsigned short)az[j]);
        }
        short8 af;
        #pragma unroll
        for (int j = 0; j < 8; j++) af[j] = (short)f2bf(vals[j]);
        #pragma unroll
        for (int tp = 0; tp < 4; tp++) {
            const int t = ch * 4 + tp;
            short8 bo = *(const short8*)(Wop + ((long)(s * 16 + t) * 64 + lane) * 8);
            acc[tp] = __builtin_amdgcn_mfma_f32_16x16x32_bf16(af, bo, acc[tp], 0, 0, 0);
        }
    }

    #pragma unroll
    for (int tp = 0; tp < 4; tp++) {
        #pragma unroll
        for (int r = 0; r < 4; r++)
            out[(i0 + quad * 4 + r) * C_DIM + (ch * 4 + tp) * 16 + l15] = acc[tp][r];
    }
}

// ---------------------------------------------------------------------------
extern "C" void kernel_launch(void* const* d_in, const int* in_sizes, int n_in,
                              void* d_out, int out_size, void* d_ws, size_t ws_size,
                              hipStream_t stream)
{
    const float* query   = (const float*)d_in[0];
    const float* context = (const float*)d_in[1];
    const float* Wq      = (const float*)d_in[2];
    const float* Wk      = (const float*)d_in[3];
    const float* Wv      = (const float*)d_in[4];
    const float* Wo      = (const float*)d_in[5];
    float* out = (float*)d_out;

    char* ws = (char*)d_ws;
    unsigned short* Qb = (unsigned short*)(ws);                    // 2 MB [bh][n][32]
    unsigned short* Kb = (unsigned short*)(ws + (2 << 20));        // 2 MB [bh][n][32]
    unsigned short* Vb = (unsigned short*)(ws + (4 << 20));        // 2 MB [bh][32][n]
    unsigned short* AO = (unsigned short*)(ws + (6 << 20));        // 8 MB [4][b*n][128] bf16
    float*          Lb = (float*)(ws + (22 << 20));                // 512 KB [4][bh][n]
    unsigned short* Wp = (unsigned short*)(ws + (23 << 20));       // 256 KB packed

    wpack_kernel<<<dim3(64), dim3(256), 0, stream>>>(Wq, Wk, Wv, Wo, Wp);
    qkv_kernel<<<dim3(512), dim3(256), 0, stream>>>(query, context, Wp, Qb, Kb, Vb);
    attn_kernel<<<dim3(32 * BH * SPLITS), dim3(256), 0, stream>>>(
        Qb, Kb, Vb, AO, Lb);
    outproj_kernel<<<dim3(512), dim3(256), 0, stream>>>(AO, Lb, Wp, out);
}